// Round 1
// baseline (35.052 us; speedup 1.0000x reference)
//
#include <hip/hip_runtime.h>
#include <math.h>

#define W      704
#define K      11
#define NBX    64          // 704 / 11
#define NSTRIPS 2048       // 32 images * 64 strips
#define NF4    176         // 704 / 4 float4 per row
#define PAD_W  708         // 704 + 4 pad: breaks bank aliasing, keeps 16B align
#define NBLOCKS_TOTAL 131072.0f   // 32 * 64 * 64
#define C_CONST 0.0009f

__global__ __launch_bounds__(256) void vif_strip_kernel(
    const float* __restrict__ vis,
    const float* __restrict__ inf,
    const float* __restrict__ fus,
    float* __restrict__ strip_sums)
{
    __shared__ float scol[8][PAD_W];   // per-column sums of the 8 quantities
    __shared__ float sred[NBX][8];     // per-block sums

    const int t = threadIdx.x;
    const int strip = blockIdx.x;                 // 0..2047
    const size_t base = (size_t)strip * (K * W);  // strips are contiguous

    if (t < NF4) {
        float acc[8][4];
        #pragma unroll
        for (int q = 0; q < 8; ++q)
            #pragma unroll
            for (int c = 0; c < 4; ++c) acc[q][c] = 0.f;

        const float4* vp = (const float4*)(vis + base) + t;
        const float4* ip = (const float4*)(inf + base) + t;
        const float4* fp = (const float4*)(fus + base) + t;

        #pragma unroll
        for (int r = 0; r < K; ++r) {
            float4 v4 = vp[(size_t)r * NF4];
            float4 i4 = ip[(size_t)r * NF4];
            float4 f4 = fp[(size_t)r * NF4];
            float vv[4] = {v4.x, v4.y, v4.z, v4.w};
            float ii[4] = {i4.x, i4.y, i4.z, i4.w};
            float ff[4] = {f4.x, f4.y, f4.z, f4.w};
            #pragma unroll
            for (int c = 0; c < 4; ++c) {
                float v = vv[c], i = ii[c], f = ff[c];
                acc[0][c] += v;     acc[1][c] += i;     acc[2][c] += f;
                acc[3][c] += v * v; acc[4][c] += i * i; acc[5][c] += f * f;
                acc[6][c] += v * f; acc[7][c] += i * f;
            }
        }
        #pragma unroll
        for (int q = 0; q < 8; ++q) {
            float4 w4 = make_float4(acc[q][0], acc[q][1], acc[q][2], acc[q][3]);
            *(float4*)&scol[q][4 * t] = w4;   // 16B-aligned (PAD_W*4 % 16 == 0)
        }
    }
    __syncthreads();

    // 64 blocks * 8 quantities = 512 reduction tasks over 11 columns each
    for (int task = t; task < NBX * 8; task += 256) {
        int bx = task >> 3, q = task & 7;
        float s = 0.f;
        #pragma unroll
        for (int j = 0; j < K; ++j) s += scol[q][bx * K + j];
        sred[bx][q] = s;
    }
    __syncthreads();

    float score = 0.f;
    if (t < NBX) {
        const float invn = 1.0f / 121.0f;
        float mv = sred[t][0] * invn;
        float mi = sred[t][1] * invn;
        float mf = sred[t][2] * invn;
        float var_v = fabsf(sred[t][3] * invn - mv * mv);
        float var_i = fabsf(sred[t][4] * invn - mi * mi);
        float var_f = fabsf(sred[t][5] * invn - mf * mf);
        float cov_vf = sred[t][6] * invn - mv * mf;
        float cov_if = sred[t][7] * invn - mi * mf;

        float l_vf = (2.f * mv * mf + C_CONST) / (mv * mv + mf * mf + C_CONST);
        float l_if = (2.f * mi * mf + C_CONST) / (mi * mi + mf * mf + C_CONST);
        float s_vf = (cov_vf + C_CONST) / (var_v + var_f + C_CONST);
        float s_if = (cov_if + C_CONST) / (var_i + var_f + C_CONST);

        score = (mv > mi) ? (l_vf * s_vf) : (l_if * s_if);
    }

    // threads 0..63 are exactly wave 0 — deterministic shuffle reduce
    if (t < 64) {
        #pragma unroll
        for (int off = 32; off > 0; off >>= 1)
            score += __shfl_down(score, off);
        if (t == 0) strip_sums[strip] = score;
    }
}

__global__ __launch_bounds__(256) void vif_reduce_kernel(
    const float* __restrict__ strip_sums,
    float* __restrict__ out)
{
    __shared__ float red[4];
    const int t = threadIdx.x;
    float s = 0.f;
    for (int i = t; i < NSTRIPS; i += 256) s += strip_sums[i];
    #pragma unroll
    for (int off = 32; off > 0; off >>= 1)
        s += __shfl_down(s, off);
    int wave = t >> 6;
    if ((t & 63) == 0) red[wave] = s;
    __syncthreads();
    if (t == 0) {
        float tot = red[0] + red[1] + red[2] + red[3];
        out[0] = 1.0f - tot / NBLOCKS_TOTAL;
    }
}

extern "C" void kernel_launch(void* const* d_in, const int* in_sizes, int n_in,
                              void* d_out, int out_size, void* d_ws, size_t ws_size,
                              hipStream_t stream)
{
    const float* vis = (const float*)d_in[0];
    const float* inf = (const float*)d_in[1];
    const float* fus = (const float*)d_in[2];
    float* out = (float*)d_out;
    float* strip_sums = (float*)d_ws;   // 2048 floats = 8 KB

    vif_strip_kernel<<<NSTRIPS, 256, 0, stream>>>(vis, inf, fus, strip_sums);
    vif_reduce_kernel<<<1, 256, 0, stream>>>(strip_sums, out);
}

// Round 2
// 34.349 us; speedup vs baseline: 1.0205x; 1.0205x over previous
//
#include <hip/hip_runtime.h>
#include <math.h>

#define W       704
#define K       11
#define NBX     64            // 704 / 11 blocks per strip
#define NSTRIPS 2048          // 32 images * 64 strips
#define NBLK    1024          // workgroups; each handles 2 strips
#define NC2     352           // 704 / 2 float2 per row
#define PAD_W   708           // padded scol leading dim (even -> 8B-aligned f2 stores)
#define NTOT    131072.0f     // 32 * 64 * 64 output blocks
#define C_CONST 0.0009f

__device__ __forceinline__ void load_accum(
    const float* __restrict__ vis, const float* __restrict__ inf,
    const float* __restrict__ fus, size_t base, int c, float acc[8][2])
{
    #pragma unroll
    for (int q = 0; q < 8; ++q) { acc[q][0] = 0.f; acc[q][1] = 0.f; }
    const float2* vp = (const float2*)(vis + base) + c;
    const float2* ip = (const float2*)(inf + base) + c;
    const float2* fp = (const float2*)(fus + base) + c;
    #pragma unroll
    for (int r = 0; r < K; ++r) {
        float2 v2 = vp[r * NC2];
        float2 i2 = ip[r * NC2];
        float2 f2 = fp[r * NC2];
        acc[0][0] += v2.x;        acc[0][1] += v2.y;
        acc[1][0] += i2.x;        acc[1][1] += i2.y;
        acc[2][0] += f2.x;        acc[2][1] += f2.y;
        acc[3][0] += v2.x * v2.x; acc[3][1] += v2.y * v2.y;
        acc[4][0] += i2.x * i2.x; acc[4][1] += i2.y * i2.y;
        acc[5][0] += f2.x * f2.x; acc[5][1] += f2.y * f2.y;
        acc[6][0] += v2.x * f2.x; acc[6][1] += v2.y * f2.y;
        acc[7][0] += i2.x * f2.x; acc[7][1] += i2.y * f2.y;
    }
}

__global__ __launch_bounds__(384) void vif_strip_kernel(
    const float* __restrict__ vis,
    const float* __restrict__ inf,
    const float* __restrict__ fus,
    float* __restrict__ block_sums)
{
    __shared__ float scol[8][PAD_W];   // per-column sums of the 8 quantities
    __shared__ float sred[NBX][8];     // per-11x11-block sums

    const int t = threadIdx.x;
    const int s0 = 2 * blockIdx.x;                   // first strip of this block
    const size_t base0 = (size_t)s0 * (K * W);
    const size_t base1 = base0 + (size_t)(K * W);

    const bool loader = (t < NC2);
    float acc0[8][2], acc1[8][2];
    float scoreSum = 0.f;
    const float invn = 1.0f / 121.0f;

    // ---- phase 0: load strip 0, stage columns ----
    if (loader) {
        load_accum(vis, inf, fus, base0, t, acc0);
        #pragma unroll
        for (int q = 0; q < 8; ++q)
            *(float2*)&scol[q][2 * t] = make_float2(acc0[q][0], acc0[q][1]);
    }
    __syncthreads();

    // issue strip-1 global loads now — they overlap the reduce/score below
    if (loader) load_accum(vis, inf, fus, base1, t, acc1);

    // reduce strip 0 columns -> per-block sums
    for (int task = t; task < NBX * 8; task += 384) {
        int bx = task >> 3, q = task & 7;
        float s = 0.f;
        #pragma unroll
        for (int j = 0; j < K; ++j) s += scol[q][bx * K + j];
        sred[bx][q] = s;
    }
    __syncthreads();

    if (t < NBX) {
        float mv = sred[t][0] * invn, mi = sred[t][1] * invn, mf = sred[t][2] * invn;
        float var_v = fabsf(sred[t][3] * invn - mv * mv);
        float var_i = fabsf(sred[t][4] * invn - mi * mi);
        float var_f = fabsf(sred[t][5] * invn - mf * mf);
        float cov_vf = sred[t][6] * invn - mv * mf;
        float cov_if = sred[t][7] * invn - mi * mf;
        float l_vf = (2.f * mv * mf + C_CONST) / (mv * mv + mf * mf + C_CONST);
        float l_if = (2.f * mi * mf + C_CONST) / (mi * mi + mf * mf + C_CONST);
        float s_vf = (cov_vf + C_CONST) / (var_v + var_f + C_CONST);
        float s_if = (cov_if + C_CONST) / (var_i + var_f + C_CONST);
        scoreSum += (mv > mi) ? (l_vf * s_vf) : (l_if * s_if);
    }

    // ---- phase 1: stage strip 1 columns (scol free after the reduce sync) ----
    if (loader) {
        #pragma unroll
        for (int q = 0; q < 8; ++q)
            *(float2*)&scol[q][2 * t] = make_float2(acc1[q][0], acc1[q][1]);
    }
    __syncthreads();   // also orders the t<NBX sred reads above vs. rewrite below

    for (int task = t; task < NBX * 8; task += 384) {
        int bx = task >> 3, q = task & 7;
        float s = 0.f;
        #pragma unroll
        for (int j = 0; j < K; ++j) s += scol[q][bx * K + j];
        sred[bx][q] = s;
    }
    __syncthreads();

    if (t < NBX) {
        float mv = sred[t][0] * invn, mi = sred[t][1] * invn, mf = sred[t][2] * invn;
        float var_v = fabsf(sred[t][3] * invn - mv * mv);
        float var_i = fabsf(sred[t][4] * invn - mi * mi);
        float var_f = fabsf(sred[t][5] * invn - mf * mf);
        float cov_vf = sred[t][6] * invn - mv * mf;
        float cov_if = sred[t][7] * invn - mi * mf;
        float l_vf = (2.f * mv * mf + C_CONST) / (mv * mv + mf * mf + C_CONST);
        float l_if = (2.f * mi * mf + C_CONST) / (mi * mi + mf * mf + C_CONST);
        float s_vf = (cov_vf + C_CONST) / (var_v + var_f + C_CONST);
        float s_if = (cov_if + C_CONST) / (var_i + var_f + C_CONST);
        scoreSum += (mv > mi) ? (l_vf * s_vf) : (l_if * s_if);
    }

    // threads 0..63 are exactly wave 0 — deterministic shuffle reduce
    if (t < 64) {
        #pragma unroll
        for (int off = 32; off > 0; off >>= 1)
            scoreSum += __shfl_down(scoreSum, off);
        if (t == 0) block_sums[blockIdx.x] = scoreSum;
    }
}

__global__ __launch_bounds__(256) void vif_reduce_kernel(
    const float* __restrict__ block_sums,
    float* __restrict__ out)
{
    __shared__ float red[4];
    const int t = threadIdx.x;
    float s = 0.f;
    for (int i = t; i < NBLK; i += 256) s += block_sums[i];
    #pragma unroll
    for (int off = 32; off > 0; off >>= 1)
        s += __shfl_down(s, off);
    int wave = t >> 6;
    if ((t & 63) == 0) red[wave] = s;
    __syncthreads();
    if (t == 0) {
        float tot = red[0] + red[1] + red[2] + red[3];
        out[0] = 1.0f - tot / NTOT;
    }
}

extern "C" void kernel_launch(void* const* d_in, const int* in_sizes, int n_in,
                              void* d_out, int out_size, void* d_ws, size_t ws_size,
                              hipStream_t stream)
{
    const float* vis = (const float*)d_in[0];
    const float* inf = (const float*)d_in[1];
    const float* fus = (const float*)d_in[2];
    float* out = (float*)d_out;
    float* block_sums = (float*)d_ws;   // 1024 floats = 4 KB

    vif_strip_kernel<<<NBLK, 384, 0, stream>>>(vis, inf, fus, block_sums);
    vif_reduce_kernel<<<1, 256, 0, stream>>>(block_sums, out);
}